// Round 1
// baseline (662.421 us; speedup 1.0000x reference)
//
#include <hip/hip_runtime.h>
#include <hip/hip_bf16.h>
#include <cstdint>

#define TOKENS 8192
#define IN_F 4096
#define OUT_F 4096

typedef __bf16 bf16x8 __attribute__((ext_vector_type(8)));
typedef float f32x4 __attribute__((ext_vector_type(4)));

// ---------------------------------------------------------------------------
// Pass A: last-write-wins scatter, step 1 — max nnz-index per touched cell.
// M was memset to 0xFF (= -1) beforehand; i >= 0 always wins.
// ---------------------------------------------------------------------------
__global__ void scatter_max_kernel(const int* __restrict__ row,
                                   const int* __restrict__ col,
                                   int* __restrict__ M, int nnz) {
    int i = blockIdx.x * blockDim.x + threadIdx.x;
    if (i < nnz) {
        atomicMax(&M[row[i] * IN_F + col[i]], i);
    }
}

// ---------------------------------------------------------------------------
// Pass B: write the winning (last) weight, converted to bf16.
// Wb was memset to 0 (bf16 zero) beforehand.
// ---------------------------------------------------------------------------
__global__ void scatter_write_kernel(const int* __restrict__ row,
                                     const int* __restrict__ col,
                                     const float* __restrict__ w,
                                     const int* __restrict__ M,
                                     __bf16* __restrict__ Wb, int nnz) {
    int i = blockIdx.x * blockDim.x + threadIdx.x;
    if (i < nnz) {
        int cell = row[i] * IN_F + col[i];
        if (M[cell] == i) Wb[cell] = (__bf16)w[i];
    }
}

// ---------------------------------------------------------------------------
// x fp32 -> bf16, 8 elements/thread (2x float4 in, 16B out).
// ---------------------------------------------------------------------------
__global__ void convert_x_kernel(const float* __restrict__ x,
                                 __bf16* __restrict__ xb) {
    int i = (blockIdx.x * blockDim.x + threadIdx.x) * 8;
    float4 v0 = *(const float4*)(x + i);
    float4 v1 = *(const float4*)(x + i + 4);
    bf16x8 o;
    o[0] = (__bf16)v0.x; o[1] = (__bf16)v0.y;
    o[2] = (__bf16)v0.z; o[3] = (__bf16)v0.w;
    o[4] = (__bf16)v1.x; o[5] = (__bf16)v1.y;
    o[6] = (__bf16)v1.z; o[7] = (__bf16)v1.w;
    *(bf16x8*)(xb + i) = o;
}

// ---------------------------------------------------------------------------
// GEMM: C[M,N] = A[M,K] * B[N,K]^T + bias  (m97 structure)
// 128x128 tile, BK=32, 256 threads = 4 waves, each wave 64x64 via 4x4 of
// 16x16x32 bf16 MFMA. global_load_lds width=16 staging, single-buffered.
// LDS layout: As/Bs row-major [128][32] bf16, no padding (global_load_lds
// writes wave-uniform base + lane*16B, which matches chunk*512 + lane*8 elems).
// ---------------------------------------------------------------------------
__global__ __launch_bounds__(256) void gemm_bt_kernel(
    const __bf16* __restrict__ A,   // [TOKENS, IN_F]
    const __bf16* __restrict__ B,   // [OUT_F, IN_F]  (W row-major = B^T form)
    const float* __restrict__ bias, // [OUT_F]
    float* __restrict__ C) {        // [TOKENS, OUT_F]
    __shared__ __bf16 As[128 * 32];
    __shared__ __bf16 Bs[128 * 32];

    const int tid  = threadIdx.x;
    const int lane = tid & 63;
    const int wid  = tid >> 6;           // 0..3
    const int m0 = blockIdx.y * 128;
    const int n0 = blockIdx.x * 128;
    const int wm = (wid >> 1) * 64;      // wave's m-quadrant
    const int wn = (wid & 1) * 64;       // wave's n-quadrant

    // Staging: tile = 8 chunks of 1024B (16 rows x 32 bf16). Wave w stages
    // chunks 2w, 2w+1 of both As and Bs. Lane l covers row l/4, cols (l%4)*8.
    const int srow = lane >> 2;
    const int scol = (lane & 3) * 8;
    const int c0 = wid * 2, c1 = wid * 2 + 1;

    const __bf16* ga0 = A + (size_t)(m0 + c0 * 16 + srow) * IN_F + scol;
    const __bf16* ga1 = A + (size_t)(m0 + c1 * 16 + srow) * IN_F + scol;
    const __bf16* gb0 = B + (size_t)(n0 + c0 * 16 + srow) * IN_F + scol;
    const __bf16* gb1 = B + (size_t)(n0 + c1 * 16 + srow) * IN_F + scol;

    __bf16* la0 = &As[c0 * 512];  // wave-uniform LDS bases
    __bf16* la1 = &As[c1 * 512];
    __bf16* lb0 = &Bs[c0 * 512];
    __bf16* lb1 = &Bs[c1 * 512];

    // Fragment addresses: A-operand lane l holds A[m = lane&15][k = (l>>4)*8 + j]
    const int fm = lane & 15;
    const int fq = (lane >> 4) * 8;
    const __bf16* fa = &As[(wm + fm) * 32 + fq];
    const __bf16* fb = &Bs[(wn + fm) * 32 + fq];

    f32x4 acc[4][4] = {};

    for (int kt = 0; kt < IN_F; kt += 32) {
        __builtin_amdgcn_global_load_lds(
            (unsigned int __attribute__((address_space(1)))*)(ga0 + kt),
            (unsigned int __attribute__((address_space(3)))*)la0, 16, 0, 0);
        __builtin_amdgcn_global_load_lds(
            (unsigned int __attribute__((address_space(1)))*)(ga1 + kt),
            (unsigned int __attribute__((address_space(3)))*)la1, 16, 0, 0);
        __builtin_amdgcn_global_load_lds(
            (unsigned int __attribute__((address_space(1)))*)(gb0 + kt),
            (unsigned int __attribute__((address_space(3)))*)lb0, 16, 0, 0);
        __builtin_amdgcn_global_load_lds(
            (unsigned int __attribute__((address_space(1)))*)(gb1 + kt),
            (unsigned int __attribute__((address_space(3)))*)lb1, 16, 0, 0);

        __syncthreads();  // drains vmcnt, staging visible to all waves

        bf16x8 afrag[4], bfrag[4];
#pragma unroll
        for (int t = 0; t < 4; ++t) afrag[t] = *(const bf16x8*)(fa + t * 512);
#pragma unroll
        for (int t = 0; t < 4; ++t) bfrag[t] = *(const bf16x8*)(fb + t * 512);

#pragma unroll
        for (int mt = 0; mt < 4; ++mt)
#pragma unroll
            for (int nt = 0; nt < 4; ++nt)
                acc[mt][nt] = __builtin_amdgcn_mfma_f32_16x16x32_bf16(
                    afrag[mt], bfrag[nt], acc[mt][nt], 0, 0, 0);

        __syncthreads();  // LDS consumed; safe to overwrite next iter
    }

    // Epilogue: C/D layout col = lane&15, row = (lane>>4)*4 + reg (m89/m91).
    float bv[4];
#pragma unroll
    for (int nt = 0; nt < 4; ++nt) bv[nt] = bias[n0 + wn + nt * 16 + fm];
    const int r0 = m0 + wm + (lane >> 4) * 4;
#pragma unroll
    for (int mt = 0; mt < 4; ++mt)
#pragma unroll
        for (int nt = 0; nt < 4; ++nt) {
            const int cc = n0 + wn + nt * 16 + fm;
#pragma unroll
            for (int i = 0; i < 4; ++i) {
                C[(size_t)(r0 + mt * 16 + i) * OUT_F + cc] = acc[mt][nt][i] + bv[nt];
            }
        }
}

extern "C" void kernel_launch(void* const* d_in, const int* in_sizes, int n_in,
                              void* d_out, int out_size, void* d_ws, size_t ws_size,
                              hipStream_t stream) {
    const float* x    = (const float*)d_in[0];
    const float* w    = (const float*)d_in[1];
    const float* bias = (const float*)d_in[2];
    const int*   row  = (const int*)d_in[3];
    const int*   col  = (const int*)d_in[4];
    float* out = (float*)d_out;
    const int nnz = in_sizes[3];

    // Workspace layout: xb (67 MB) + Wb (33.5 MB) in d_ws; M (67 MB) borrows
    // d_out (134 MB) as scratch — the GEMM fully overwrites d_out afterwards.
    __bf16* xb = (__bf16*)d_ws;
    __bf16* Wb = (__bf16*)((char*)d_ws + (size_t)TOKENS * IN_F * 2);
    int* M = (int*)d_out;

    hipMemsetAsync(Wb, 0, (size_t)OUT_F * IN_F * 2, stream);           // W = 0
    hipMemsetAsync(M, 0xFF, (size_t)OUT_F * IN_F * 4, stream);         // M = -1

    int sblocks = (nnz + 255) / 256;
    scatter_max_kernel<<<sblocks, 256, 0, stream>>>(row, col, M, nnz);
    scatter_write_kernel<<<sblocks, 256, 0, stream>>>(row, col, w, M, Wb, nnz);

    convert_x_kernel<<<(TOKENS * IN_F / 8 + 255) / 256, 256, 0, stream>>>(x, xb);

    dim3 grid(OUT_F / 128, TOKENS / 128);  // x: N-tiles (32), y: M-tiles (64)
    gemm_bt_kernel<<<grid, 256, 0, stream>>>(xb, Wb, bias, out);
}

// Round 2
// 634.053 us; speedup vs baseline: 1.0447x; 1.0447x over previous
//
#include <hip/hip_runtime.h>
#include <hip/hip_bf16.h>
#include <cstdint>

#define TOKENS 8192
#define IN_F 4096
#define OUT_F 4096

typedef __bf16 bf16x8 __attribute__((ext_vector_type(8)));
typedef float f32x4 __attribute__((ext_vector_type(4)));

// ---------------------------------------------------------------------------
// One-pass last-write-wins scatter via packed 64-bit atomicMax.
// pack = (nnz_index << 16) | bf16_bits(weight). Index in high bits => max
// over packs implements "last write wins"; winning weight rides in low 16.
// P memset to 0 beforehand; untouched cells stay 0 => bf16 +0.0.
// ---------------------------------------------------------------------------
__global__ void scatter_pack_kernel(const int* __restrict__ row,
                                    const int* __restrict__ col,
                                    const float* __restrict__ w,
                                    unsigned long long* __restrict__ P,
                                    int nnz) {
    int i = blockIdx.x * blockDim.x + threadIdx.x;
    if (i < nnz) {
        __bf16 b = (__bf16)w[i];
        unsigned short bits;
        __builtin_memcpy(&bits, &b, 2);
        unsigned long long pack =
            ((unsigned long long)(unsigned)i << 16) | (unsigned long long)bits;
        atomicMax(&P[(size_t)row[i] * IN_F + col[i]], pack);
    }
}

// ---------------------------------------------------------------------------
// Fused streaming pass: blocks [0, eb) extract bf16 weights from P's low 16
// bits (writes EVERY cell -> no Wb memset needed); blocks [eb, ...) convert
// x fp32 -> bf16. 8 elements/thread both halves.
// ---------------------------------------------------------------------------
__global__ void extract_convert_kernel(const unsigned long long* __restrict__ P,
                                       __bf16* __restrict__ Wb,
                                       const float* __restrict__ x,
                                       __bf16* __restrict__ xb,
                                       int eb) {
    if ((int)blockIdx.x < eb) {
        size_t base = ((size_t)blockIdx.x * 256 + threadIdx.x) * 8;
        bf16x8 o;
#pragma unroll
        for (int j = 0; j < 8; ++j) {
            unsigned short bits = (unsigned short)(P[base + j] & 0xFFFFull);
            __bf16 b;
            __builtin_memcpy(&b, &bits, 2);
            o[j] = b;
        }
        *(bf16x8*)(Wb + base) = o;
    } else {
        size_t base = ((size_t)(blockIdx.x - eb) * 256 + threadIdx.x) * 8;
        float4 v0 = *(const float4*)(x + base);
        float4 v1 = *(const float4*)(x + base + 4);
        bf16x8 o;
        o[0] = (__bf16)v0.x; o[1] = (__bf16)v0.y;
        o[2] = (__bf16)v0.z; o[3] = (__bf16)v0.w;
        o[4] = (__bf16)v1.x; o[5] = (__bf16)v1.y;
        o[6] = (__bf16)v1.z; o[7] = (__bf16)v1.w;
        *(bf16x8*)(xb + base) = o;
    }
}

// ---------------------------------------------------------------------------
// GEMM: C[M,N] = A[M,K] * B[N,K]^T + bias  (m97 structure, unchanged from R1)
// 128x128 tile, BK=32, 256 threads = 4 waves, each wave 64x64 via 4x4 of
// 16x16x32 bf16 MFMA. global_load_lds width=16 staging, single-buffered.
// ---------------------------------------------------------------------------
__global__ __launch_bounds__(256) void gemm_bt_kernel(
    const __bf16* __restrict__ A,   // [TOKENS, IN_F]
    const __bf16* __restrict__ B,   // [OUT_F, IN_F]
    const float* __restrict__ bias, // [OUT_F]
    float* __restrict__ C) {        // [TOKENS, OUT_F]
    __shared__ __bf16 As[128 * 32];
    __shared__ __bf16 Bs[128 * 32];

    const int tid  = threadIdx.x;
    const int lane = tid & 63;
    const int wid  = tid >> 6;           // 0..3
    const int m0 = blockIdx.y * 128;
    const int n0 = blockIdx.x * 128;
    const int wm = (wid >> 1) * 64;
    const int wn = (wid & 1) * 64;

    const int srow = lane >> 2;
    const int scol = (lane & 3) * 8;
    const int c0 = wid * 2, c1 = wid * 2 + 1;

    const __bf16* ga0 = A + (size_t)(m0 + c0 * 16 + srow) * IN_F + scol;
    const __bf16* ga1 = A + (size_t)(m0 + c1 * 16 + srow) * IN_F + scol;
    const __bf16* gb0 = B + (size_t)(n0 + c0 * 16 + srow) * IN_F + scol;
    const __bf16* gb1 = B + (size_t)(n0 + c1 * 16 + srow) * IN_F + scol;

    __bf16* la0 = &As[c0 * 512];
    __bf16* la1 = &As[c1 * 512];
    __bf16* lb0 = &Bs[c0 * 512];
    __bf16* lb1 = &Bs[c1 * 512];

    const int fm = lane & 15;
    const int fq = (lane >> 4) * 8;
    const __bf16* fa = &As[(wm + fm) * 32 + fq];
    const __bf16* fb = &Bs[(wn + fm) * 32 + fq];

    f32x4 acc[4][4] = {};

    for (int kt = 0; kt < IN_F; kt += 32) {
        __builtin_amdgcn_global_load_lds(
            (unsigned int __attribute__((address_space(1)))*)(ga0 + kt),
            (unsigned int __attribute__((address_space(3)))*)la0, 16, 0, 0);
        __builtin_amdgcn_global_load_lds(
            (unsigned int __attribute__((address_space(1)))*)(ga1 + kt),
            (unsigned int __attribute__((address_space(3)))*)la1, 16, 0, 0);
        __builtin_amdgcn_global_load_lds(
            (unsigned int __attribute__((address_space(1)))*)(gb0 + kt),
            (unsigned int __attribute__((address_space(3)))*)lb0, 16, 0, 0);
        __builtin_amdgcn_global_load_lds(
            (unsigned int __attribute__((address_space(1)))*)(gb1 + kt),
            (unsigned int __attribute__((address_space(3)))*)lb1, 16, 0, 0);

        __syncthreads();

        bf16x8 afrag[4], bfrag[4];
#pragma unroll
        for (int t = 0; t < 4; ++t) afrag[t] = *(const bf16x8*)(fa + t * 512);
#pragma unroll
        for (int t = 0; t < 4; ++t) bfrag[t] = *(const bf16x8*)(fb + t * 512);

#pragma unroll
        for (int mt = 0; mt < 4; ++mt)
#pragma unroll
            for (int nt = 0; nt < 4; ++nt)
                acc[mt][nt] = __builtin_amdgcn_mfma_f32_16x16x32_bf16(
                    afrag[mt], bfrag[nt], acc[mt][nt], 0, 0, 0);

        __syncthreads();
    }

    float bv[4];
#pragma unroll
    for (int nt = 0; nt < 4; ++nt) bv[nt] = bias[n0 + wn + nt * 16 + fm];
    const int r0 = m0 + wm + (lane >> 4) * 4;
#pragma unroll
    for (int mt = 0; mt < 4; ++mt)
#pragma unroll
        for (int nt = 0; nt < 4; ++nt) {
            const int cc = n0 + wn + nt * 16 + fm;
#pragma unroll
            for (int i = 0; i < 4; ++i) {
                C[(size_t)(r0 + mt * 16 + i) * OUT_F + cc] = acc[mt][nt][i] + bv[nt];
            }
        }
}

extern "C" void kernel_launch(void* const* d_in, const int* in_sizes, int n_in,
                              void* d_out, int out_size, void* d_ws, size_t ws_size,
                              hipStream_t stream) {
    const float* x    = (const float*)d_in[0];
    const float* w    = (const float*)d_in[1];
    const float* bias = (const float*)d_in[2];
    const int*   row  = (const int*)d_in[3];
    const int*   col  = (const int*)d_in[4];
    float* out = (float*)d_out;
    const int nnz = in_sizes[3];

    // Workspace: xb (67 MB) + Wb (33.5 MB) in d_ws. Packed scatter array P
    // (16.78M x 8B = 134.2 MB) borrows d_out (8192*4096*4 = 134.2 MB, exact
    // fit) — the GEMM fully overwrites d_out afterwards.
    __bf16* xb = (__bf16*)d_ws;
    __bf16* Wb = (__bf16*)((char*)d_ws + (size_t)TOKENS * IN_F * 2);
    unsigned long long* P = (unsigned long long*)d_out;

    hipMemsetAsync(P, 0, (size_t)OUT_F * IN_F * 8, stream);

    scatter_pack_kernel<<<(nnz + 255) / 256, 256, 0, stream>>>(row, col, w, P, nnz);

    const int eb = OUT_F * IN_F / (256 * 8);        // 8192 extract blocks
    const int cb = TOKENS * IN_F / (256 * 8);       // 16384 convert blocks
    extract_convert_kernel<<<eb + cb, 256, 0, stream>>>(P, Wb, x, xb, eb);

    dim3 grid(OUT_F / 128, TOKENS / 128);
    gemm_bt_kernel<<<grid, 256, 0, stream>>>(xb, Wb, bias, out);
}

// Round 3
// 624.151 us; speedup vs baseline: 1.0613x; 1.0159x over previous
//
#include <hip/hip_runtime.h>
#include <hip/hip_bf16.h>
#include <cstdint>

#define TOKENS 8192
#define IN_F 4096
#define OUT_F 4096

typedef __bf16 bf16x8 __attribute__((ext_vector_type(8)));
typedef float f32x4 __attribute__((ext_vector_type(4)));

// ---------------------------------------------------------------------------
// Last-write-wins scatter, 32-bit: M[cell] = max nnz-index touching cell.
// M memset to 0xFF (= -1) beforehand; i >= 0 always wins. No w read here.
// ---------------------------------------------------------------------------
__global__ void scatter_max_kernel(const int* __restrict__ row,
                                   const int* __restrict__ col,
                                   int* __restrict__ M, int nnz) {
    int i = blockIdx.x * blockDim.x + threadIdx.x;
    if (i < nnz) {
        atomicMax(&M[(size_t)row[i] * IN_F + col[i]], i);
    }
}

// ---------------------------------------------------------------------------
// Fused streaming pass: blocks [0, eb) read M sequentially, gather the
// winning weight w[idx] (w is 6.5 MB -> L2-resident) and write bf16 W
// (every cell written -> no W memset). Blocks [eb, ...) convert x fp32->bf16.
// ---------------------------------------------------------------------------
__global__ void extract_convert_kernel(const int* __restrict__ M,
                                       const float* __restrict__ w,
                                       __bf16* __restrict__ Wb,
                                       const float* __restrict__ x,
                                       __bf16* __restrict__ xb,
                                       int eb) {
    if ((int)blockIdx.x < eb) {
        size_t base = ((size_t)blockIdx.x * 256 + threadIdx.x) * 8;
        int4 m0 = *(const int4*)(M + base);
        int4 m1 = *(const int4*)(M + base + 4);
        int idx[8] = {m0.x, m0.y, m0.z, m0.w, m1.x, m1.y, m1.z, m1.w};
        bf16x8 o;
#pragma unroll
        for (int j = 0; j < 8; ++j) {
            o[j] = (idx[j] >= 0) ? (__bf16)w[idx[j]] : (__bf16)0.0f;
        }
        *(bf16x8*)(Wb + base) = o;
    } else {
        size_t base = ((size_t)(blockIdx.x - eb) * 256 + threadIdx.x) * 8;
        float4 v0 = *(const float4*)(x + base);
        float4 v1 = *(const float4*)(x + base + 4);
        bf16x8 o;
        o[0] = (__bf16)v0.x; o[1] = (__bf16)v0.y;
        o[2] = (__bf16)v0.z; o[3] = (__bf16)v0.w;
        o[4] = (__bf16)v1.x; o[5] = (__bf16)v1.y;
        o[6] = (__bf16)v1.z; o[7] = (__bf16)v1.w;
        *(bf16x8*)(xb + base) = o;
    }
}

// ---------------------------------------------------------------------------
// GEMM: C[M,N] = A[M,K] * B[N,K]^T + bias  (m97 structure + XOR bank swizzle)
// 128x128 tile, BK=32, 256 threads = 4 waves, each wave 64x64 via 4x4 of
// 16x16x32 bf16 MFMA. global_load_lds width=16 staging, single-buffered.
//
// Bank swizzle: LDS slot (row r, 16B-chunk p) holds logical chunk
// q = p ^ ((r>>1)&3). Staging implements this by permuting the GLOBAL source
// column per lane (within-64B permutation -> still coalesced); readers use
// chunk = (lane>>4) ^ ((fm>>1)&3), which is invariant across the 4 m/n
// subtiles (row stride 16 doesn't touch row bits 1-2). This spreads the
// 16-lane read phases across all 32 banks at 2-way (free) instead of 8-way.
// ---------------------------------------------------------------------------
__global__ __launch_bounds__(256) void gemm_bt_kernel(
    const __bf16* __restrict__ A,   // [TOKENS, IN_F]
    const __bf16* __restrict__ B,   // [OUT_F, IN_F]
    const float* __restrict__ bias, // [OUT_F]
    float* __restrict__ C) {        // [TOKENS, OUT_F]
    __shared__ __bf16 As[128 * 32];
    __shared__ __bf16 Bs[128 * 32];

    const int tid  = threadIdx.x;
    const int lane = tid & 63;
    const int wid  = tid >> 6;           // 0..3
    const int m0 = blockIdx.y * 128;
    const int n0 = blockIdx.x * 128;
    const int wm = (wid >> 1) * 64;
    const int wn = (wid & 1) * 64;

    // Staging: chunk c covers rows c*16..c*16+15. Lane l -> row l>>2, source
    // col chunk (l&3) ^ ((l>>3)&3)  [swizzled], LDS dest = chunk_base + l*16B.
    const int srow = lane >> 2;
    const int scol = (((lane & 3) ^ ((lane >> 3) & 3)) * 8);
    const int c0 = wid * 2, c1 = wid * 2 + 1;

    const __bf16* ga0 = A + (size_t)(m0 + c0 * 16 + srow) * IN_F + scol;
    const __bf16* ga1 = A + (size_t)(m0 + c1 * 16 + srow) * IN_F + scol;
    const __bf16* gb0 = B + (size_t)(n0 + c0 * 16 + srow) * IN_F + scol;
    const __bf16* gb1 = B + (size_t)(n0 + c1 * 16 + srow) * IN_F + scol;

    __bf16* la0 = &As[c0 * 512];
    __bf16* la1 = &As[c1 * 512];
    __bf16* lb0 = &Bs[c0 * 512];
    __bf16* lb1 = &Bs[c1 * 512];

    // Fragment reads: logical chunk j = lane>>4 lives at LDS chunk
    // j ^ ((fm>>1)&3) within row wm+fm (+16t).
    const int fm = lane & 15;
    const int fc = (((lane >> 4) ^ ((fm >> 1) & 3)) * 8);
    const __bf16* fa = &As[(wm + fm) * 32 + fc];
    const __bf16* fb = &Bs[(wn + fm) * 32 + fc];

    f32x4 acc[4][4] = {};

    for (int kt = 0; kt < IN_F; kt += 32) {
        __builtin_amdgcn_global_load_lds(
            (unsigned int __attribute__((address_space(1)))*)(ga0 + kt),
            (unsigned int __attribute__((address_space(3)))*)la0, 16, 0, 0);
        __builtin_amdgcn_global_load_lds(
            (unsigned int __attribute__((address_space(1)))*)(ga1 + kt),
            (unsigned int __attribute__((address_space(3)))*)la1, 16, 0, 0);
        __builtin_amdgcn_global_load_lds(
            (unsigned int __attribute__((address_space(1)))*)(gb0 + kt),
            (unsigned int __attribute__((address_space(3)))*)lb0, 16, 0, 0);
        __builtin_amdgcn_global_load_lds(
            (unsigned int __attribute__((address_space(1)))*)(gb1 + kt),
            (unsigned int __attribute__((address_space(3)))*)lb1, 16, 0, 0);

        __syncthreads();

        bf16x8 afrag[4], bfrag[4];
#pragma unroll
        for (int t = 0; t < 4; ++t) afrag[t] = *(const bf16x8*)(fa + t * 512);
#pragma unroll
        for (int t = 0; t < 4; ++t) bfrag[t] = *(const bf16x8*)(fb + t * 512);

#pragma unroll
        for (int mt = 0; mt < 4; ++mt)
#pragma unroll
            for (int nt = 0; nt < 4; ++nt)
                acc[mt][nt] = __builtin_amdgcn_mfma_f32_16x16x32_bf16(
                    afrag[mt], bfrag[nt], acc[mt][nt], 0, 0, 0);

        __syncthreads();
    }

    float bv[4];
#pragma unroll
    for (int nt = 0; nt < 4; ++nt) bv[nt] = bias[n0 + wn + nt * 16 + fm];
    const int r0 = m0 + wm + (lane >> 4) * 4;
#pragma unroll
    for (int mt = 0; mt < 4; ++mt)
#pragma unroll
        for (int nt = 0; nt < 4; ++nt) {
            const int cc = n0 + wn + nt * 16 + fm;
#pragma unroll
            for (int i = 0; i < 4; ++i) {
                C[(size_t)(r0 + mt * 16 + i) * OUT_F + cc] = acc[mt][nt][i] + bv[nt];
            }
        }
}

extern "C" void kernel_launch(void* const* d_in, const int* in_sizes, int n_in,
                              void* d_out, int out_size, void* d_ws, size_t ws_size,
                              hipStream_t stream) {
    const float* x    = (const float*)d_in[0];
    const float* w    = (const float*)d_in[1];
    const float* bias = (const float*)d_in[2];
    const int*   row  = (const int*)d_in[3];
    const int*   col  = (const int*)d_in[4];
    float* out = (float*)d_out;
    const int nnz = in_sizes[3];

    // Workspace: xb (67 MB) + Wb (33.5 MB) in d_ws. Winner-index array M
    // (16.78M x 4B = 67 MB) borrows d_out (134 MB) — GEMM overwrites it later.
    __bf16* xb = (__bf16*)d_ws;
    __bf16* Wb = (__bf16*)((char*)d_ws + (size_t)TOKENS * IN_F * 2);
    int* M = (int*)d_out;

    hipMemsetAsync(M, 0xFF, (size_t)OUT_F * IN_F * 4, stream);  // M = -1

    scatter_max_kernel<<<(nnz + 255) / 256, 256, 0, stream>>>(row, col, M, nnz);

    const int eb = OUT_F * IN_F / (256 * 8);        // 8192 extract blocks
    const int cb = TOKENS * IN_F / (256 * 8);       // 16384 convert blocks
    extract_convert_kernel<<<eb + cb, 256, 0, stream>>>(M, w, Wb, x, xb, eb);

    dim3 grid(OUT_F / 128, TOKENS / 128);
    gemm_bt_kernel<<<grid, 256, 0, stream>>>(xb, Wb, bias, out);
}